// Round 3
// baseline (554.397 us; speedup 1.0000x reference)
//
#include <hip/hip_runtime.h>

// LSTM forward, fused: T=2048, B=1024, I=15, H=10 (PyTorch gate order i,f,g,o).
// One wave per batch row; 1024 waves = 1 wave/SIMD (structural; serial over T).
// Lane layout: lane = 4*j + p, j=hidden unit, p=gate (i,f,g,o).
// Gate combine via DPP quad_perm; h broadcast via readlane->SGPR.
// waves_per_eu(1,1): we are at 1 wave/SIMD anyway -> give allocator 512 VGPRs
// so wih/whh/xq stay in arch VGPRs (round 2 showed 36 VGPRs => spill traffic
// on the serial chain).
// Outputs buffered in an LDS ring, flushed every 32 steps with 5 coalesced
// 64-lane stores -> recurrent loop's vmcnt queue holds only x-prefetch loads.

#define T_N 2048
#define B_N 1024
#define I_N 15
#define H_N 10
#define DQ 8   // x prefetch queue depth
#define FB 32  // output flush block (steps)

template <int CTRL>
static __device__ __forceinline__ float qb(float v) {
    // quad_perm broadcast within each group of 4 lanes
    return __builtin_bit_cast(float,
        __builtin_amdgcn_mov_dpp(__builtin_bit_cast(int, v), CTRL, 0xF, 0xF, true));
}
static __device__ __forceinline__ float rl(float v, int lane) {
    return __builtin_bit_cast(float, __builtin_amdgcn_readlane(__builtin_bit_cast(int, v), lane));
}

__global__ __launch_bounds__(64)
__attribute__((amdgpu_waves_per_eu(1, 1)))
void lstm_fused(const float* __restrict__ x, const float* __restrict__ h0,
                const float* __restrict__ c0, const float* __restrict__ Wih,
                const float* __restrict__ Whh, float* __restrict__ out)
{
    __shared__ float ring[FB * H_N + 64];  // 320 real slots + 64-dword dump area

    const int b = blockIdx.x;
    const int lane = threadIdx.x;
    const int p = lane & 3;              // gate: 0=i 1=f 2=g 3=o
    int j = lane >> 2; if (j > H_N - 1) j = H_N - 1;  // lanes 40..63 dup unit 9
    const int row = p * H_N + j;         // W row (PyTorch: [i;f;g;o] blocks of 10)
    const bool isTanh = (p == 2);
    const float LOG2E = 1.4426950408889634f;
    // Fold activation-argument scale into the weight rows:
    //  sigmoid(z) = 1/(1+exp2(-z*log2e))     -> scale = -log2e,  act = r
    //  tanh(z)    = 1 - 2/(1+exp2(2z*log2e)) -> scale = +2log2e, act = 1-2r
    const float sg   = isTanh ? 2.0f * LOG2E : -LOG2E;
    const float Aact = isTanh ? -2.0f : 1.0f;
    const float Bact = isTanh ?  1.0f : 0.0f;

    float wih[I_N];
#pragma unroll
    for (int i = 0; i < I_N; ++i) wih[i] = sg * Wih[row * I_N + i];
    float whh[H_N];
#pragma unroll
    for (int q = 0; q < H_N; ++q) whh[q] = sg * Whh[row * H_N + q];

    // Every lane of quad j tracks c/h for unit j (redundant, divergence-free)
    float c = c0[b * H_N + j];
    float h = h0[b * H_N + j];
    float hs[H_N];  // wave-uniform SGPR copies of h[0..9] (unit q lives at lane 4q)
#pragma unroll
    for (int q = 0; q < H_N; ++q) hs[q] = rl(h, 4 * q);

    // x prefetch queue: lanes 0..14 carry x[t][b][lane]; others dup element 0
    const int xk = lane < I_N ? lane : 0;
    float xq[DQ];
#pragma unroll
    for (int d = 0; d < DQ; ++d)
        xq[d] = x[((size_t)d * B_N + b) * I_N + xk];

    const bool writer = (p == 0) && (lane < 4 * H_N);
    // LDS ring slot: writers hit (t%32)*10+j, everyone else a distinct dump slot
    const int dumpSlot = FB * H_N + lane;

    // Flush mapping: 320 ring floats -> out[tb+tq][b][jq], 5 rounds of 64 lanes
    int off[FB * H_N / 64];
#pragma unroll
    for (int r = 0; r < FB * H_N / 64; ++r) {
        const int idx = r * 64 + lane;
        off[r] = (idx / H_N) * (B_N * H_N) + (idx % H_N);
    }

    for (int tb = 0; tb < T_N; tb += FB) {
        for (int t0 = tb; t0 < tb + FB; t0 += DQ) {
#pragma unroll
            for (int d = 0; d < DQ; ++d) {
                const int t = t0 + d;
                const float xv = xq[d];
                int tq = t + DQ; if (tq > T_N - 1) tq = T_N - 1;
                xq[d] = x[((size_t)tq * B_N + b) * I_N + xk];

                // x contribution (off the recurrent chain; prefetched DQ ahead)
                float a0 = 0.f, a1 = 0.f, a2 = 0.f;
#pragma unroll
                for (int k = 0; k < 5; ++k) a0 = fmaf(rl(xv, k),      wih[k],      a0);
#pragma unroll
                for (int k = 0; k < 5; ++k) a1 = fmaf(rl(xv, k + 5),  wih[k + 5],  a1);
#pragma unroll
                for (int k = 0; k < 5; ++k) a2 = fmaf(rl(xv, k + 10), wih[k + 10], a2);
                const float xpart = (a0 + a1) + a2;

                // recurrent contribution: two parallel 5-FMA chains off SGPR h
                float a3 = 0.f, a4 = 0.f;
#pragma unroll
                for (int q = 0; q < 5; ++q) a3 = fmaf(hs[q],     whh[q],     a3);
#pragma unroll
                for (int q = 0; q < 5; ++q) a4 = fmaf(hs[q + 5], whh[q + 5], a4);
                const float acc = xpart + (a3 + a4);

                // activation: r = 1/(1+exp2(acc)); sigmoid -> r, tanh -> 1-2r
                const float e   = __builtin_amdgcn_exp2f(acc);
                const float r   = __builtin_amdgcn_rcpf(1.0f + e);
                const float act = fmaf(Aact, r, Bact);

                // gather i,f,g,o of unit j via quad broadcasts (pure VALU)
                const float iv = qb<0x00>(act);
                const float fv = qb<0x55>(act);
                const float gv = qb<0xAA>(act);
                const float ov = qb<0xFF>(act);

                // cell + hidden update (all quad lanes redundantly)
                c = fmaf(fv, c, iv * gv);
                const float tt = __builtin_amdgcn_exp2f(c * (2.0f * LOG2E));
                const float th = fmaf(-2.0f, __builtin_amdgcn_rcpf(1.0f + tt), 1.0f);
                h = ov * th;

                // stash h in the LDS ring (no global op, no branch)
                const int ridx = writer ? ((t & (FB - 1)) * H_N + j) : dumpSlot;
                ring[ridx] = h;

                // broadcast new h to SGPRs for next step (unit q at lane 4q)
#pragma unroll
                for (int q = 0; q < H_N; ++q) hs[q] = rl(h, 4 * q);
            }
        }

        // flush 32 steps of h: 5 coalesced 64-lane dword stores
        float* outBase = out + (size_t)tb * (B_N * H_N) + b * H_N;
#pragma unroll
        for (int r = 0; r < FB * H_N / 64; ++r)
            outBase[off[r]] = ring[r * 64 + lane];
    }

    // final hN, cN appended after out (flat tuple order: out, hN, cN)
    if (writer) {
        const size_t base = (size_t)T_N * B_N * H_N;
        out[base + b * H_N + j] = h;
        out[base + (size_t)B_N * H_N + b * H_N + j] = c;
    }
}

extern "C" void kernel_launch(void* const* d_in, const int* in_sizes, int n_in,
                              void* d_out, int out_size, void* d_ws, size_t ws_size,
                              hipStream_t stream) {
    const float* x   = (const float*)d_in[0];
    const float* h0  = (const float*)d_in[1];
    const float* c0  = (const float*)d_in[2];
    const float* Wih = (const float*)d_in[3];
    const float* Whh = (const float*)d_in[4];
    float* out = (float*)d_out;
    lstm_fused<<<dim3(B_N), dim3(64), 0, stream>>>(x, h0, c0, Wih, Whh, out);
}